// Round 1
// baseline (224.147 us; speedup 1.0000x reference)
//
#include <hip/hip_runtime.h>
#include <math.h>

#define NBINS 4096
#define BINSCALE 256.0f
#define BATCH 16
#define NPER (1u << 20)          // elements per sample (C*H*W)
#define TOPK 65536u              // NPER / 16
#define BLOCKS_PER_SAMPLE 64
#define THREADS 256
// per-block elements = NPER/BLOCKS_PER_SAMPLE = 16384 -> 4096 float4 -> 16 iters/thread

// workspace layout (bytes)
#define HIST_OFF    0                        // uint32 [BATCH][NBINS] = 262144 B
#define BSTAR_OFF   262144                   // int    [BATCH]
#define CABOVE_OFF  262208                   // uint32 [BATCH]
#define SUMA_OFF    262272                   // double [BATCH]
#define BSUM_OFF    262400                   // double [BATCH]
#define BCNT_OFF    262528                   // uint32 [BATCH]
#define WS_BYTES    262592

__device__ __forceinline__ float xent(float x, float lab) {
    float y   = (lab >= 0.5f) ? 1.0f : 0.0f;
    float pos = (x   >= 0.0f) ? 1.0f : 0.0f;
    float ax  = fabsf(x);
    return x * (pos - y) + log1pf(__expf(-ax));
}

__device__ __forceinline__ int binof(float v) {
    int b = (int)(v * BINSCALE);
    b = b < 0 ? 0 : (b > NBINS - 1 ? NBINS - 1 : b);
    return b;
}

__global__ void __launch_bounds__(THREADS)
hist_kernel(const float* __restrict__ outp, const float* __restrict__ labp,
            unsigned int* __restrict__ hist) {
    __shared__ unsigned int lh[NBINS];
    const int s = blockIdx.y;
    const int chunk = blockIdx.x;
    for (int i = threadIdx.x; i < NBINS; i += THREADS) lh[i] = 0u;
    __syncthreads();

    const float4* o4 = (const float4*)outp;
    const float4* l4 = (const float4*)labp;
    const size_t base4 = (size_t)s * (NPER / 4) + (size_t)chunk * 4096;
#pragma unroll 4
    for (int j = 0; j < 16; ++j) {
        size_t idx = base4 + (size_t)j * 256 + threadIdx.x;
        float4 xo = o4[idx];
        float4 xl = l4[idx];
        atomicAdd(&lh[binof(xent(xo.x, xl.x))], 1u);
        atomicAdd(&lh[binof(xent(xo.y, xl.y))], 1u);
        atomicAdd(&lh[binof(xent(xo.z, xl.z))], 1u);
        atomicAdd(&lh[binof(xent(xo.w, xl.w))], 1u);
    }
    __syncthreads();

    unsigned int* gh = hist + (size_t)s * NBINS;
    for (int i = threadIdx.x; i < NBINS; i += THREADS) {
        unsigned int c = lh[i];
        if (c) atomicAdd(&gh[i], c);
    }
}

__global__ void __launch_bounds__(THREADS)
select_kernel(const unsigned int* __restrict__ hist,
              int* __restrict__ bstar, unsigned int* __restrict__ cabove) {
    __shared__ unsigned int g[THREADS];
    const int s = blockIdx.x;
    const unsigned int* h = hist + (size_t)s * NBINS;
    const int t = threadIdx.x;

    unsigned int sum = 0;
#pragma unroll
    for (int i = 0; i < 16; ++i) sum += h[t * 16 + i];
    g[t] = sum;
    __syncthreads();

    // inclusive suffix sum: g[t] = count of elements in bins >= t*16
    for (int off = 1; off < THREADS; off <<= 1) {
        unsigned int v = (t + off < THREADS) ? g[t + off] : 0u;
        __syncthreads();
        g[t] += v;
        __syncthreads();
    }

    unsigned int above = (t + 1 < THREADS) ? g[t + 1] : 0u;
    if (g[t] >= TOPK && above < TOPK) {  // unique winner group
        unsigned int cum = above;        // count strictly above current scan point
        int bs = t * 16;
        for (int i = 15; i >= 0; --i) {
            unsigned int c = h[t * 16 + i];
            if (cum + c >= TOPK) { bs = t * 16 + i; break; }
            cum += c;
        }
        bstar[s] = bs;
        cabove[s] = cum;
    }
}

__global__ void __launch_bounds__(THREADS)
sum_kernel(const float* __restrict__ outp, const float* __restrict__ labp,
           const int* __restrict__ bstar,
           double* __restrict__ sumAbove, double* __restrict__ bsum,
           unsigned int* __restrict__ bcount) {
    const int s = blockIdx.y;
    const int chunk = blockIdx.x;
    const int bst = bstar[s];

    float sA = 0.0f, sB = 0.0f;
    unsigned int cB = 0;

    const float4* o4 = (const float4*)outp;
    const float4* l4 = (const float4*)labp;
    const size_t base4 = (size_t)s * (NPER / 4) + (size_t)chunk * 4096;
#pragma unroll 4
    for (int j = 0; j < 16; ++j) {
        size_t idx = base4 + (size_t)j * 256 + threadIdx.x;
        float4 xo = o4[idx];
        float4 xl = l4[idx];
        float v[4] = {xent(xo.x, xl.x), xent(xo.y, xl.y),
                      xent(xo.z, xl.z), xent(xo.w, xl.w)};
#pragma unroll
        for (int q = 0; q < 4; ++q) {
            int b = binof(v[q]);
            if (b > bst)       sA += v[q];
            else if (b == bst) { sB += v[q]; ++cB; }
        }
    }

    // wave reduce (64 lanes)
    for (int off = 32; off > 0; off >>= 1) {
        sA += __shfl_down(sA, off);
        sB += __shfl_down(sB, off);
        cB += __shfl_down(cB, off);
    }
    __shared__ float wsA[4], wsB[4];
    __shared__ unsigned int wcB[4];
    const int wave = threadIdx.x >> 6, lane = threadIdx.x & 63;
    if (lane == 0) { wsA[wave] = sA; wsB[wave] = sB; wcB[wave] = cB; }
    __syncthreads();
    if (threadIdx.x == 0) {
        float tA = 0.0f, tB = 0.0f; unsigned int tc = 0;
        for (int w = 0; w < 4; ++w) { tA += wsA[w]; tB += wsB[w]; tc += wcB[w]; }
        atomicAdd(&sumAbove[s], (double)tA);
        atomicAdd(&bsum[s], (double)tB);
        atomicAdd(&bcount[s], tc);
    }
}

__global__ void final_kernel(const double* __restrict__ sumAbove,
                             const double* __restrict__ bsum,
                             const unsigned int* __restrict__ bcount,
                             const unsigned int* __restrict__ cabove,
                             float* __restrict__ out) {
    __shared__ double means[BATCH];
    const int t = threadIdx.x;
    if (t < BATCH) {
        double needed = (double)(int)(TOPK - cabove[t]);
        double avg = bcount[t] ? bsum[t] / (double)bcount[t] : 0.0;
        means[t] = (sumAbove[t] + needed * avg) / (double)TOPK;
    }
    __syncthreads();
    if (t == 0) {
        double acc = 0.0;
        for (int i = 0; i < BATCH; ++i) acc += means[i];
        out[0] = (float)(acc / (double)BATCH);
    }
}

extern "C" void kernel_launch(void* const* d_in, const int* in_sizes, int n_in,
                              void* d_out, int out_size, void* d_ws, size_t ws_size,
                              hipStream_t stream) {
    const float* outp = (const float*)d_in[0];
    const float* labp = (const float*)d_in[1];
    unsigned char* ws = (unsigned char*)d_ws;

    unsigned int* hist     = (unsigned int*)(ws + HIST_OFF);
    int*          bstar    = (int*)(ws + BSTAR_OFF);
    unsigned int* cabove   = (unsigned int*)(ws + CABOVE_OFF);
    double*       sumAbove = (double*)(ws + SUMA_OFF);
    double*       bsum     = (double*)(ws + BSUM_OFF);
    unsigned int* bcount   = (unsigned int*)(ws + BCNT_OFF);

    hipMemsetAsync(d_ws, 0, WS_BYTES, stream);

    hist_kernel<<<dim3(BLOCKS_PER_SAMPLE, BATCH), THREADS, 0, stream>>>(outp, labp, hist);
    select_kernel<<<BATCH, THREADS, 0, stream>>>(hist, bstar, cabove);
    sum_kernel<<<dim3(BLOCKS_PER_SAMPLE, BATCH), THREADS, 0, stream>>>(
        outp, labp, bstar, sumAbove, bsum, bcount);
    final_kernel<<<1, 64, 0, stream>>>(sumAbove, bsum, bcount, cabove, (float*)d_out);
}

// Round 2
// 152.383 us; speedup vs baseline: 1.4709x; 1.4709x over previous
//
#include <hip/hip_runtime.h>
#include <math.h>

#define NBINS 1024
#define BINSCALE 64.0f          // bin width 1/64
#define FXSCALE 1024.0f         // fixed-point scale for value sums
#define BATCH 16
#define NPER (1u << 20)         // elements per sample
#define TOPK 65536u             // NPER / 16
#define BPS 32                  // blocks per sample
#define THREADS 256
// per block: NPER/BPS = 32768 elems = 8192 float4 = 32 iters/thread

// workspace layout (bytes)
#define CNT_OFF   0                       // uint32 [BATCH][NBINS] = 65536 B
#define SFX_OFF   65536                   // uint64 [BATCH][NBINS] = 131072 B
#define MEANS_OFF 196608                  // double [BATCH] = 128 B
#define ZERO_BYTES 196608                 // cnt + sumfx must be zeroed

__device__ __forceinline__ float xent(float x, float lab) {
    float y   = (lab >= 0.5f) ? 1.0f : 0.0f;
    float pos = (x   >= 0.0f) ? 1.0f : 0.0f;
    float ax  = fabsf(x);
    float sp  = __logf(1.0f + __expf(-ax));   // softplus(-|x|), HW exp2/log2
    return fmaf(x, pos - y, sp);              // >= 0 always
}

__global__ void __launch_bounds__(THREADS)
histsum_kernel(const float* __restrict__ outp, const float* __restrict__ labp,
               unsigned int* __restrict__ gcnt,
               unsigned long long* __restrict__ gsum) {
    __shared__ unsigned int lcnt[NBINS];
    __shared__ unsigned int lfx[NBINS];
    const int s = blockIdx.y;
    const int chunk = blockIdx.x;
    for (int i = threadIdx.x; i < NBINS; i += THREADS) { lcnt[i] = 0u; lfx[i] = 0u; }
    __syncthreads();

    const float4* o4 = (const float4*)outp;
    const float4* l4 = (const float4*)labp;
    const size_t base4 = (size_t)s * (NPER / 4) + (size_t)chunk * (NPER / 4 / BPS);
#pragma unroll 8
    for (int j = 0; j < 32; ++j) {
        size_t idx = base4 + (size_t)j * THREADS + threadIdx.x;
        float4 xo = o4[idx];
        float4 xl = l4[idx];
        float v[4] = {xent(xo.x, xl.x), xent(xo.y, xl.y),
                      xent(xo.z, xl.z), xent(xo.w, xl.w)};
#pragma unroll
        for (int q = 0; q < 4; ++q) {
            int b = (int)(v[q] * BINSCALE);
            b = b > NBINS - 1 ? NBINS - 1 : (b < 0 ? 0 : b);
            unsigned int fx = (unsigned int)__float2uint_rn(v[q] * FXSCALE);
            atomicAdd(&lcnt[b], 1u);
            atomicAdd(&lfx[b], fx);
        }
    }
    __syncthreads();

    unsigned int* gc = gcnt + (size_t)s * NBINS;
    unsigned long long* gf = gsum + (size_t)s * NBINS;
    for (int i = threadIdx.x; i < NBINS; i += THREADS) {
        unsigned int cc = lcnt[i];
        if (cc) {
            atomicAdd(&gc[i], cc);
            atomicAdd(&gf[i], (unsigned long long)lfx[i]);
        }
    }
}

__global__ void __launch_bounds__(THREADS)
select_kernel(const unsigned int* __restrict__ gcnt,
              const unsigned long long* __restrict__ gsum,
              double* __restrict__ means) {
    const int s = blockIdx.x;
    const unsigned int* c = gcnt + (size_t)s * NBINS;
    const unsigned long long* f = gsum + (size_t)s * NBINS;
    const int t = threadIdx.x;   // 256 threads, 4 consecutive bins each

    unsigned int cc[4];
#pragma unroll
    for (int i = 0; i < 4; ++i) cc[i] = c[t * 4 + i];
    __shared__ unsigned int S[THREADS];
    S[t] = cc[0] + cc[1] + cc[2] + cc[3];
    __syncthreads();

    // inclusive suffix scan: S[t] = count of elements in bins >= t*4
    for (int off = 1; off < THREADS; off <<= 1) {
        unsigned int v = (t + off < THREADS) ? S[t + off] : 0u;
        __syncthreads();
        S[t] += v;
        __syncthreads();
    }

    __shared__ int sh_bst;
    __shared__ unsigned int sh_cabove;
    unsigned int above_group = (t + 1 < THREADS) ? S[t + 1] : 0u;
    if (S[t] >= TOPK && above_group < TOPK) {   // unique winner group
        unsigned int cum = above_group;
        int bs = t * 4;
        for (int i = 3; i >= 0; --i) {
            if (cum + cc[i] >= TOPK) { bs = t * 4 + i; break; }
            cum += cc[i];
        }
        sh_bst = bs; sh_cabove = cum;
    }
    __syncthreads();
    const int bst = sh_bst;
    const unsigned int cabove = sh_cabove;

    // exact sum over bins strictly above bst
    double local = 0.0;
#pragma unroll
    for (int i = 0; i < 4; ++i) {
        int b = t * 4 + i;
        if (b > bst) local += (double)f[b];
    }
    __shared__ double R[THREADS];
    R[t] = local;
    __syncthreads();
    for (int off = THREADS / 2; off > 0; off >>= 1) {
        if (t < off) R[t] += R[t + off];
        __syncthreads();
    }
    if (t == 0) {
        double sumAbove = R[0] / (double)FXSCALE;
        double needed = (double)(TOPK - cabove);
        unsigned int cb = c[bst];
        double avg = cb ? ((double)f[bst] / (double)FXSCALE) / (double)cb : 0.0;
        means[s] = (sumAbove + needed * avg) / (double)TOPK;
    }
}

__global__ void final_kernel(const double* __restrict__ means, float* __restrict__ out) {
    if (threadIdx.x == 0) {
        double acc = 0.0;
        for (int i = 0; i < BATCH; ++i) acc += means[i];
        out[0] = (float)(acc / (double)BATCH);
    }
}

extern "C" void kernel_launch(void* const* d_in, const int* in_sizes, int n_in,
                              void* d_out, int out_size, void* d_ws, size_t ws_size,
                              hipStream_t stream) {
    const float* outp = (const float*)d_in[0];
    const float* labp = (const float*)d_in[1];
    unsigned char* ws = (unsigned char*)d_ws;

    unsigned int*       gcnt  = (unsigned int*)(ws + CNT_OFF);
    unsigned long long* gsum  = (unsigned long long*)(ws + SFX_OFF);
    double*             means = (double*)(ws + MEANS_OFF);

    hipMemsetAsync(d_ws, 0, ZERO_BYTES, stream);

    histsum_kernel<<<dim3(BPS, BATCH), THREADS, 0, stream>>>(outp, labp, gcnt, gsum);
    select_kernel<<<BATCH, THREADS, 0, stream>>>(gcnt, gsum, means);
    final_kernel<<<1, 64, 0, stream>>>(means, (float*)d_out);
}